// Round 16
// baseline (314.072 us; speedup 1.0000x reference)
//
#include <hip/hip_runtime.h>
#include <stdint.h>

#define N_NODES 50000
#define N_EDGES 1600000
#define NBLK_N 196        // ceil(50000/256)
#define NB 391            // buckets of 128 dst nodes
#define BPAD 8192         // padded bucket capacity
#define CHUNK 4096        // edges per prep workgroup
#define NWG_PREP 391      // ceil(1.6M/4096)

typedef float fvec2 __attribute__((ext_vector_type(2)));
typedef float fvec4 __attribute__((ext_vector_type(4)));

__device__ inline float bf2f(uint16_t u) {
  union { uint32_t i; float f; } c; c.i = (uint32_t)u << 16; return c.f;
}
__device__ inline uint16_t f2bf(float f) {
  union { uint32_t i; float f; } c; c.f = f;
  uint32_t b = c.i;
  b += 0x7FFFu + ((b >> 16) & 1u);   // round to nearest even
  return (uint16_t)(b >> 16);
}

// hardware OCP e4m3fn helpers (gfx950 fp8-conversion-insts)
__device__ inline uint32_t pk4_fp8(float a, float b, float c, float d) {
  a = fminf(fmaxf(a, -440.0f), 440.0f);
  b = fminf(fmaxf(b, -440.0f), 440.0f);
  c = fminf(fmaxf(c, -440.0f), 440.0f);
  d = fminf(fmaxf(d, -440.0f), 440.0f);
  int pk = __builtin_amdgcn_cvt_pk_fp8_f32(a, b, 0, false);
  pk = __builtin_amdgcn_cvt_pk_fp8_f32(c, d, pk, true);
  return (uint32_t)pk;
}

// ---------------------------------------------------------------------------
// Prep + pass-1 binning (no global cnt3 atomics)
// ---------------------------------------------------------------------------
__global__ __launch_bounds__(256) void k_prep(const int* __restrict__ ei,
                                              const float* __restrict__ ea,
                                              int* __restrict__ bcur,
                                              uint32_t* __restrict__ pairbuf) {
  __shared__ int hist[NB];
  __shared__ int hbase[NB];
  int t = threadIdx.x;
  int base = blockIdx.x * CHUNK;
  for (int i = t; i < NB; i += 256) hist[i] = 0;
  __syncthreads();

  uint32_t wreg[16];
  int breg[16];
  #pragma unroll
  for (int k = 0; k < 16; k++) {
    int e = base + t + k * 256;
    breg[k] = -1;
    if (e < N_EDGES) {
      float dist = ea[(size_t)e * 6];
      int rel = (dist > 5000.0f) + (dist > 10000.0f);
      int s = ei[e];
      int d = ei[N_EDGES + e];
      wreg[k] = (uint32_t)s | ((uint32_t)rel << 16) | ((uint32_t)(d & 127) << 24);
      breg[k] = d >> 7;
      atomicAdd(&hist[breg[k]], 1);
    }
  }
  __syncthreads();
  for (int i = t; i < NB; i += 256) {
    int h = hist[i];
    hbase[i] = h ? atomicAdd(&bcur[i], h) : 0;
    hist[i] = 0;
  }
  __syncthreads();
  #pragma unroll
  for (int k = 0; k < 16; k++) {
    int b = breg[k];
    if (b >= 0) {
      int r = atomicAdd(&hist[b], 1);
      pairbuf[(size_t)b * BPAD + hbase[b] + r] = wreg[k];
    }
  }
}

// ---------------------------------------------------------------------------
// Per-bucket (node,rel) counting -> cnt3
// ---------------------------------------------------------------------------
__global__ __launch_bounds__(256) void k_count(const uint32_t* __restrict__ pairbuf,
                                               const int* __restrict__ bcur,
                                               int* __restrict__ cnt3) {
  __shared__ int lc[384];
  int b = blockIdx.x;
  int t = threadIdx.x;
  for (int i = t; i < 384; i += 256) lc[i] = 0;
  int cnt = bcur[b];
  __syncthreads();
  const uint32_t* pb = pairbuf + (size_t)b * BPAD;
  for (int i = t; i < cnt; i += 256) {
    uint32_t w = pb[i];
    int dl  = (int)(w >> 24);
    int rel = (int)((w >> 16) & 3u);
    atomicAdd(&lc[dl * 3 + rel], 1);
  }
  __syncthreads();
  int gbase = b * 384;
  for (int j = t; j < 384; j += 256) {
    int node = (b << 7) + (j / 3);
    if (node < N_NODES) cnt3[gbase + j] = lc[j];
  }
}

// ---------------------------------------------------------------------------
// Parallel scan of node degrees
// ---------------------------------------------------------------------------
__global__ __launch_bounds__(256) void k_scanA(const int* __restrict__ cnt3,
                                               int* __restrict__ excl,
                                               int* __restrict__ bsum) {
  __shared__ int s[256];
  int t = threadIdx.x;
  int n = blockIdx.x * 256 + t;
  int deg = 0;
  if (n < N_NODES) deg = cnt3[3 * n] + cnt3[3 * n + 1] + cnt3[3 * n + 2];
  s[t] = deg;
  __syncthreads();
  for (int ofs = 1; ofs < 256; ofs <<= 1) {
    int v = (t >= ofs) ? s[t - ofs] : 0;
    __syncthreads();
    s[t] += v;
    __syncthreads();
  }
  if (n < N_NODES) excl[n] = s[t] - deg;
  if (t == 255) bsum[blockIdx.x] = s[255];
}

__global__ __launch_bounds__(256) void k_scanB(int* __restrict__ bsum) {
  __shared__ int s[256];
  int t = threadIdx.x;
  int v = (t < NBLK_N) ? bsum[t] : 0;
  s[t] = v;
  __syncthreads();
  for (int ofs = 1; ofs < 256; ofs <<= 1) {
    int u = (t >= ofs) ? s[t - ofs] : 0;
    __syncthreads();
    s[t] += u;
    __syncthreads();
  }
  if (t < NBLK_N) bsum[t] = s[t] - v;   // exclusive
}

__global__ __launch_bounds__(256) void k_scanC(const int* __restrict__ cnt3,
                                               const int* __restrict__ excl,
                                               const int* __restrict__ bsum,
                                               int4* __restrict__ meta,
                                               const float* __restrict__ x,
                                               float4* __restrict__ x4) {
  int n = blockIdx.x * 256 + threadIdx.x;
  if (n >= N_NODES) return;
  meta[n] = make_int4(bsum[blockIdx.x] + excl[n],
                      cnt3[3 * n], cnt3[3 * n + 1], cnt3[3 * n + 2]);
  x4[n] = make_float4(x[n * 3], x[n * 3 + 1], x[n * 3 + 2], 0.0f);
}

// ---------------------------------------------------------------------------
// Pass-2 scatter
// ---------------------------------------------------------------------------
__global__ __launch_bounds__(256) void k_scat2(const uint32_t* __restrict__ pairbuf,
                                               const int* __restrict__ bcur,
                                               const int4* __restrict__ meta,
                                               uint32_t* __restrict__ csr) {
  __shared__ int lcur[128];
  int b = blockIdx.x;
  int t = threadIdx.x;
  int node0 = b << 7;
  if (t < 128) {
    int n = node0 + t;
    lcur[t] = (n < N_NODES) ? meta[n].x : 0;
  }
  int cnt = bcur[b];
  __syncthreads();
  const uint32_t* pb = pairbuf + (size_t)b * BPAD;
  for (int i = t; i < cnt; i += 256) {
    uint32_t w = pb[i];
    int dl = (int)(w >> 24);
    int p = atomicAdd(&lcur[dl], 1);
    csr[p] = w & 0x00FFFFFFu;   // src | rel<<16
  }
}

// ---------------------------------------------------------------------------
// Layer 0: din=3. Wave per node; writes f32 h + fp8 shadow (64 B rows).
// ---------------------------------------------------------------------------
__global__ __launch_bounds__(256) void k_layer0(const float4* __restrict__ x4,
                                                const float* __restrict__ W0,
                                                const float* __restrict__ root0,
                                                const float* __restrict__ b0,
                                                const int4* __restrict__ meta,
                                                const uint32_t* __restrict__ csr,
                                                float* __restrict__ hout,
                                                uint8_t* __restrict__ hf8) {
  __shared__ float sW[576], sR[192], sb[64];
  int t = threadIdx.x;
  for (int i = t; i < 576; i += 256) sW[i] = W0[i];
  for (int i = t; i < 192; i += 256) sR[i] = root0[i];
  if (t < 64) sb[t] = b0[t];
  __syncthreads();
  int wid = t >> 6, lane = t & 63;
  int n = blockIdx.x * 4 + wid;
  int4 md = meta[n];
  int off = md.x, c0 = md.y, c1 = md.z, c2 = md.w;
  int cnt = c0 + c1 + c2;
  float a00 = 0, a01 = 0, a02 = 0, a10 = 0, a11 = 0, a12 = 0, a20 = 0, a21 = 0, a22 = 0;
  for (int base = 0; base < cnt; base += 64) {
    int idx = base + lane;
    float4 v = make_float4(0, 0, 0, 0);
    int r = 3;
    if (idx < cnt) {
      uint32_t u = csr[off + idx];
      r = (int)(u >> 16);
      v = x4[u & 0xFFFFu];
    }
    a00 += (r == 0) ? v.x : 0.0f; a01 += (r == 0) ? v.y : 0.0f; a02 += (r == 0) ? v.z : 0.0f;
    a10 += (r == 1) ? v.x : 0.0f; a11 += (r == 1) ? v.y : 0.0f; a12 += (r == 1) ? v.z : 0.0f;
    a20 += (r == 2) ? v.x : 0.0f; a21 += (r == 2) ? v.y : 0.0f; a22 += (r == 2) ? v.z : 0.0f;
  }
  #pragma unroll
  for (int d = 1; d < 64; d <<= 1) {
    a00 += __shfl_xor(a00, d); a01 += __shfl_xor(a01, d); a02 += __shfl_xor(a02, d);
    a10 += __shfl_xor(a10, d); a11 += __shfl_xor(a11, d); a12 += __shfl_xor(a12, d);
    a20 += __shfl_xor(a20, d); a21 += __shfl_xor(a21, d); a22 += __shfl_xor(a22, d);
  }
  float i0 = 1.0f / (float)(c0 > 1 ? c0 : 1);
  float i1 = 1.0f / (float)(c1 > 1 ? c1 : 1);
  float i2 = 1.0f / (float)(c2 > 1 ? c2 : 1);
  float4 xn = x4[n];
  float in[12];
  in[0] = xn.x; in[1] = xn.y; in[2] = xn.z;
  in[3] = a00 * i0; in[4] = a01 * i0; in[5] = a02 * i0;
  in[6] = a10 * i1; in[7] = a11 * i1; in[8] = a12 * i1;
  in[9] = a20 * i2; in[10] = a21 * i2; in[11] = a22 * i2;
  float acc = sb[lane];
  #pragma unroll
  for (int k = 0; k < 3; k++) acc = fmaf(in[k], sR[k * 64 + lane], acc);
  #pragma unroll
  for (int k = 0; k < 9; k++) acc = fmaf(in[3 + k], sW[k * 64 + lane], acc);
  float h = fmaxf(acc, 0.0f);
  hout[(size_t)n * 64 + lane] = h;
  float hc = fminf(h, 440.0f);
  int p8 = __builtin_amdgcn_cvt_pk_fp8_f32(hc, hc, 0, false);
  hf8[(size_t)n * 64 + lane] = (uint8_t)(p8 & 0xFF);
}

// ---------------------------------------------------------------------------
// Aggregation: wave per node, lane = feature, fp8 gathers; bf16 mean output.
// ---------------------------------------------------------------------------
#define ACC(E, V) { int r_ = (int)((E) >> 16); \
  a0 += (r_ == 0) ? (V) : 0.0f; a1 += (r_ == 1) ? (V) : 0.0f; a2 += (r_ == 2) ? (V) : 0.0f; }

__global__ __launch_bounds__(256) void k_agg(const uint8_t* __restrict__ hf8,
                                             const int4* __restrict__ meta,
                                             const uint32_t* __restrict__ csr,
                                             uint16_t* __restrict__ mbuf) {
  int t = threadIdx.x, wid = t >> 6, lane = t & 63;
  int n = blockIdx.x * 4 + wid;
  int4 md = meta[n];
  int off = __builtin_amdgcn_readfirstlane(md.x);
  int c0  = __builtin_amdgcn_readfirstlane(md.y);
  int c1  = __builtin_amdgcn_readfirstlane(md.z);
  int c2  = __builtin_amdgcn_readfirstlane(md.w);
  int cnt = c0 + c1 + c2;
  const uint32_t* cp = csr + off;
  float a0 = 0, a1 = 0, a2 = 0;
  int i = 0;
  for (; i + 8 <= cnt; i += 8) {
    uint32_t e0 = cp[i],     e1 = cp[i + 1], e2 = cp[i + 2], e3 = cp[i + 3];
    uint32_t e4 = cp[i + 4], e5 = cp[i + 5], e6 = cp[i + 6], e7 = cp[i + 7];
    int b0 = hf8[(int)((e0 & 0xFFFFu) << 6) + lane];
    int b1 = hf8[(int)((e1 & 0xFFFFu) << 6) + lane];
    int b2 = hf8[(int)((e2 & 0xFFFFu) << 6) + lane];
    int b3 = hf8[(int)((e3 & 0xFFFFu) << 6) + lane];
    int b4 = hf8[(int)((e4 & 0xFFFFu) << 6) + lane];
    int b5 = hf8[(int)((e5 & 0xFFFFu) << 6) + lane];
    int b6 = hf8[(int)((e6 & 0xFFFFu) << 6) + lane];
    int b7 = hf8[(int)((e7 & 0xFFFFu) << 6) + lane];
    float v0 = __builtin_amdgcn_cvt_f32_fp8(b0, 0);
    float v1 = __builtin_amdgcn_cvt_f32_fp8(b1, 0);
    float v2 = __builtin_amdgcn_cvt_f32_fp8(b2, 0);
    float v3 = __builtin_amdgcn_cvt_f32_fp8(b3, 0);
    float v4 = __builtin_amdgcn_cvt_f32_fp8(b4, 0);
    float v5 = __builtin_amdgcn_cvt_f32_fp8(b5, 0);
    float v6 = __builtin_amdgcn_cvt_f32_fp8(b6, 0);
    float v7 = __builtin_amdgcn_cvt_f32_fp8(b7, 0);
    ACC(e0, v0) ACC(e1, v1) ACC(e2, v2) ACC(e3, v3)
    ACC(e4, v4) ACC(e5, v5) ACC(e6, v6) ACC(e7, v7)
  }
  for (; i < cnt; i++) {
    uint32_t e = cp[i];
    int b = hf8[(int)((e & 0xFFFFu) << 6) + lane];
    float v = __builtin_amdgcn_cvt_f32_fp8(b, 0);
    ACC(e, v)
  }
  uint16_t* mb = mbuf + (size_t)n * 192;
  mb[lane]       = f2bf(a0 * (1.0f / (float)(c0 > 1 ? c0 : 1)));
  mb[64 + lane]  = f2bf(a1 * (1.0f / (float)(c1 > 1 ? c1 : 1)));
  mb[128 + lane] = f2bf(a2 * (1.0f / (float)(c2 > 1 ? c2 : 1)));
}

// ---------------------------------------------------------------------------
// Transform GEMM: BM=32 tile. A = [h(f32) | means(bf16)]. Epilogue f32 h
// (+ optional fp8 shadow).
// ---------------------------------------------------------------------------
__global__ __launch_bounds__(256) void k_gemm(const float* __restrict__ hin,
                                              const uint16_t* __restrict__ mbuf,
                                              const float* __restrict__ W,
                                              const float* __restrict__ root,
                                              const float* __restrict__ b,
                                              float* __restrict__ hout,
                                              uint8_t* __restrict__ hf8) {
  __shared__ float As[32 * 84];
  __shared__ float Bs[64 * 64];
  __shared__ float sb[64];
  int t = threadIdx.x;
  int bn = blockIdx.x * 32;
  if (t < 64) sb[t] = b[t];
  int tn = t & 15, to = t >> 4;
  float acc[2][4] = {};
  for (int kb = 0; kb < 4; kb++) {
    const float4* Bsrc = (const float4*)((kb == 0) ? root : (W + (size_t)(kb - 1) * 4096));
    for (int i2 = t; i2 < 1024; i2 += 256) ((float4*)Bs)[i2] = Bsrc[i2];
    int r = t >> 3;                   // 32 rows, 8 threads/row
    int node = bn + r;
    bool ok = node < N_NODES;
    if (kb == 0) {
      const float* Arow = hin + (size_t)node * 64;
      #pragma unroll
      for (int ii = 0; ii < 2; ii++) {
        int c4 = (t & 7) + 8 * ii;
        float4 v = ok ? ((const float4*)Arow)[c4] : make_float4(0, 0, 0, 0);
        *(float4*)&As[r * 84 + c4 * 4] = v;
      }
    } else {
      int c8 = t & 7;                 // 8 bf16 per thread
      const uint16_t* Mrow = mbuf + (size_t)node * 192 + (size_t)(kb - 1) * 64 + c8 * 8;
      uint4 mv = ok ? *(const uint4*)Mrow : make_uint4(0, 0, 0, 0);
      const uint32_t* mw = &mv.x;
      float f[8];
      #pragma unroll
      for (int jj = 0; jj < 4; jj++) {
        f[2 * jj]     = bf2f((uint16_t)(mw[jj] & 0xFFFFu));
        f[2 * jj + 1] = bf2f((uint16_t)(mw[jj] >> 16));
      }
      *(float4*)&As[r * 84 + c8 * 8]     = make_float4(f[0], f[1], f[2], f[3]);
      *(float4*)&As[r * 84 + c8 * 8 + 4] = make_float4(f[4], f[5], f[6], f[7]);
    }
    __syncthreads();
    #pragma unroll
    for (int k4 = 0; k4 < 16; k4++) {
      float4 a0 = *(const float4*)&As[(tn)      * 84 + k4 * 4];
      float4 a1 = *(const float4*)&As[(tn + 16) * 84 + k4 * 4];
      float4 b0 = *(const float4*)&Bs[(k4 * 4 + 0) * 64 + to * 4];
      float4 b1 = *(const float4*)&Bs[(k4 * 4 + 1) * 64 + to * 4];
      float4 b2 = *(const float4*)&Bs[(k4 * 4 + 2) * 64 + to * 4];
      float4 b3 = *(const float4*)&Bs[(k4 * 4 + 3) * 64 + to * 4];
      const float* av[2] = {&a0.x, &a1.x};
      const float* bv[4] = {&b0.x, &b1.x, &b2.x, &b3.x};
      #pragma unroll
      for (int c = 0; c < 4; c++)
        #pragma unroll
        for (int i3 = 0; i3 < 2; i3++)
          #pragma unroll
          for (int j = 0; j < 4; j++)
            acc[i3][j] = fmaf(av[i3][c], bv[c][j], acc[i3][j]);
    }
    __syncthreads();
  }
  #pragma unroll
  for (int i3 = 0; i3 < 2; i3++) {
    int node = bn + tn + 16 * i3;
    if (node < N_NODES) {
      float4 o;
      o.x = fmaxf(acc[i3][0] + sb[to * 4 + 0], 0.0f);
      o.y = fmaxf(acc[i3][1] + sb[to * 4 + 1], 0.0f);
      o.z = fmaxf(acc[i3][2] + sb[to * 4 + 2], 0.0f);
      o.w = fmaxf(acc[i3][3] + sb[to * 4 + 3], 0.0f);
      *(float4*)(hout + (size_t)node * 64 + to * 4) = o;
      if (hf8) {
        uint32_t pk = pk4_fp8(o.x, o.y, o.z, o.w);
        *(uint32_t*)(hf8 + (size_t)node * 64 + to * 4) = pk;
      }
    }
  }
}

// ---------------------------------------------------------------------------
// P/Q projection GEMM (BM=32): fp8 e4m3fn outputs, hardware encode.
// ---------------------------------------------------------------------------
__global__ __launch_bounds__(256) void k_pq2(const float* __restrict__ h,
                                             const float* __restrict__ dw1,
                                             const float* __restrict__ db1,
                                             uint8_t* __restrict__ Pb,
                                             uint8_t* __restrict__ Qb) {
  __shared__ float As[32 * 84];
  __shared__ float Bs[64 * 64];
  __shared__ float sdb1[32];
  int t = threadIdx.x;
  int bn = blockIdx.x * 32;
  if (t < 32) sdb1[t] = db1[t];
  {
    int r = t >> 3;
    int node = bn + r;
    bool ok = node < N_NODES;
    const float* Arow = h + (size_t)node * 64;
    #pragma unroll
    for (int ii = 0; ii < 2; ii++) {
      int c4 = (t & 7) + 8 * ii;
      float4 v = ok ? ((const float4*)Arow)[c4] : make_float4(0, 0, 0, 0);
      *(float4*)&As[r * 84 + c4 * 4] = v;
    }
  }
  for (int i = t; i < 4096; i += 256) {
    int k = i >> 6, j = i & 63;
    Bs[i] = (j < 32) ? dw1[k * 32 + j] : dw1[(64 + k) * 32 + (j - 32)];
  }
  __syncthreads();
  int tn = t & 15, to = t >> 4;
  float acc[2][4] = {};
  #pragma unroll
  for (int k4 = 0; k4 < 16; k4++) {
    float4 a0 = *(const float4*)&As[(tn)      * 84 + k4 * 4];
    float4 a1 = *(const float4*)&As[(tn + 16) * 84 + k4 * 4];
    float4 b0 = *(const float4*)&Bs[(k4 * 4 + 0) * 64 + to * 4];
    float4 b1 = *(const float4*)&Bs[(k4 * 4 + 1) * 64 + to * 4];
    float4 b2 = *(const float4*)&Bs[(k4 * 4 + 2) * 64 + to * 4];
    float4 b3 = *(const float4*)&Bs[(k4 * 4 + 3) * 64 + to * 4];
    const float* av[2] = {&a0.x, &a1.x};
    const float* bv[4] = {&b0.x, &b1.x, &b2.x, &b3.x};
    #pragma unroll
    for (int c = 0; c < 4; c++)
      #pragma unroll
      for (int i3 = 0; i3 < 2; i3++)
        #pragma unroll
        for (int j = 0; j < 4; j++)
          acc[i3][j] = fmaf(av[i3][c], bv[c][j], acc[i3][j]);
  }
  bool isP = (to < 8);
  float bias0 = isP ? sdb1[to * 4 + 0] : 0.0f;
  float bias1 = isP ? sdb1[to * 4 + 1] : 0.0f;
  float bias2 = isP ? sdb1[to * 4 + 2] : 0.0f;
  float bias3 = isP ? sdb1[to * 4 + 3] : 0.0f;
  #pragma unroll
  for (int i3 = 0; i3 < 2; i3++) {
    int node = bn + tn + 16 * i3;
    if (node < N_NODES) {
      uint32_t pk = pk4_fp8(acc[i3][0] + bias0, acc[i3][1] + bias1,
                            acc[i3][2] + bias2, acc[i3][3] + bias3);
      if (isP) *(uint32_t*)(Pb + (size_t)node * 32 + to * 4) = pk;
      else     *(uint32_t*)(Qb + (size_t)node * 32 + (to - 8) * 4) = pk;
    }
  }
}

// ---------------------------------------------------------------------------
// Decoder edge pass: fp8 P/Q gathers, HW pk decode, packed-f32 (v_pk_fma) math
// ---------------------------------------------------------------------------
__global__ __launch_bounds__(256) void k_dec(const int* __restrict__ ei,
                                             const float* __restrict__ ea,
                                             const uint8_t* __restrict__ Pb,
                                             const uint8_t* __restrict__ Qb,
                                             const float* __restrict__ dw1,
                                             const float* __restrict__ dw2,
                                             const float* __restrict__ db2,
                                             const float* __restrict__ dw3,
                                             const float* __restrict__ db3,
                                             float* __restrict__ out) {
  __shared__ float C[6 * 32], W2T[16 * 32], sb2[16], W3[16];
  __shared__ float sb3;
  int t = threadIdx.x;
  for (int i = t; i < 192; i += 256) C[i] = dw1[128 * 32 + i];
  for (int i = t; i < 512; i += 256) {
    int r = i >> 5, c = i & 31;            // W2T[r][c] = dw2[c][r]
    W2T[i] = dw2[c * 16 + r];
  }
  if (t < 16) { sb2[t] = db2[t]; W3[t] = dw3[t]; }
  if (t == 0) sb3 = db3[0];
  __syncthreads();
  int e = blockIdx.x * 256 + t;
  int s = ei[e];
  int d = ei[N_EDGES + e];
  float ea6[6];
  #pragma unroll
  for (int i = 0; i < 6; i++) ea6[i] = ea[(size_t)e * 6 + i];
  uint4 pv0 = *(const uint4*)(Pb + (size_t)s * 32);
  uint4 pv1 = *(const uint4*)(Pb + (size_t)s * 32 + 16);
  uint4 qv0 = *(const uint4*)(Qb + (size_t)d * 32);
  uint4 qv1 = *(const uint4*)(Qb + (size_t)d * 32 + 16);
  uint32_t pw[8] = {pv0.x, pv0.y, pv0.z, pv0.w, pv1.x, pv1.y, pv1.z, pv1.w};
  uint32_t qw[8] = {qv0.x, qv0.y, qv0.z, qv0.w, qv1.x, qv1.y, qv1.z, qv1.w};
  fvec2 z1v[16];
  #pragma unroll
  for (int w = 0; w < 8; w++) {
    fvec2 pl = __builtin_amdgcn_cvt_pk_f32_fp8((int)pw[w], false);
    fvec2 ph = __builtin_amdgcn_cvt_pk_f32_fp8((int)pw[w], true);
    fvec2 ql = __builtin_amdgcn_cvt_pk_f32_fp8((int)qw[w], false);
    fvec2 qh = __builtin_amdgcn_cvt_pk_f32_fp8((int)qw[w], true);
    fvec2 v01 = pl + ql;
    fvec2 v23 = ph + qh;
    #pragma unroll
    for (int k = 0; k < 6; k++) {
      fvec4 cv = *(const fvec4*)&C[k * 32 + w * 4];
      fvec2 clo = __builtin_shufflevector(cv, cv, 0, 1);
      fvec2 chi = __builtin_shufflevector(cv, cv, 2, 3);
      fvec2 sk = {ea6[k], ea6[k]};
      v01 = __builtin_elementwise_fma(sk, clo, v01);
      v23 = __builtin_elementwise_fma(sk, chi, v23);
    }
    fvec2 zero = {0.0f, 0.0f};
    z1v[w * 2]     = __builtin_elementwise_max(v01, zero);
    z1v[w * 2 + 1] = __builtin_elementwise_max(v23, zero);
  }
  float o = sb3;
  #pragma unroll
  for (int i = 0; i < 16; i++) {
    fvec2 zacc = {sb2[i], 0.0f};
    #pragma unroll
    for (int j4 = 0; j4 < 8; j4++) {
      fvec4 wv = *(const fvec4*)&W2T[i * 32 + j4 * 4];
      fvec2 wlo = __builtin_shufflevector(wv, wv, 0, 1);
      fvec2 whi = __builtin_shufflevector(wv, wv, 2, 3);
      zacc = __builtin_elementwise_fma(z1v[j4 * 2],     wlo, zacc);
      zacc = __builtin_elementwise_fma(z1v[j4 * 2 + 1], whi, zacc);
    }
    float z = zacc.x + zacc.y;
    o = fmaf(fmaxf(z, 0.0f), W3[i], o);
  }
  out[e] = o;
}

// ---------------------------------------------------------------------------
extern "C" void kernel_launch(void* const* d_in, const int* in_sizes, int n_in,
                              void* d_out, int out_size, void* d_ws, size_t ws_size,
                              hipStream_t stream) {
  const float* x      = (const float*)d_in[0];
  const int*   ei     = (const int*)d_in[1];
  const float* ea     = (const float*)d_in[2];
  const float* w0     = (const float*)d_in[3];
  const float* root0  = (const float*)d_in[4];
  const float* b0     = (const float*)d_in[5];
  const float* w1     = (const float*)d_in[6];
  const float* root1  = (const float*)d_in[7];
  const float* b1     = (const float*)d_in[8];
  const float* w2     = (const float*)d_in[9];
  const float* root2  = (const float*)d_in[10];
  const float* b2     = (const float*)d_in[11];
  const float* dw1    = (const float*)d_in[12];
  const float* db1    = (const float*)d_in[13];
  const float* dw2    = (const float*)d_in[14];
  const float* db2    = (const float*)d_in[15];
  const float* dw3    = (const float*)d_in[16];
  const float* db3    = (const float*)d_in[17];
  float* out = (float*)d_out;

  char* w = (char*)d_ws;
  int* cnt3        = (int*)w;       w += (size_t)N_NODES * 3 * 4;
  int* bcur        = (int*)w;       w += (size_t)NB * 4;
  int4* meta       = (int4*)w;      w += (size_t)N_NODES * 16;
  uint32_t* csr    = (uint32_t*)w;  w += (size_t)N_EDGES * 4;
  float4* x4       = (float4*)w;    w += (size_t)N_NODES * 16;
  float* h1        = (float*)w;     w += (size_t)N_NODES * 64 * 4;
  float* h2        = (float*)w;     w += (size_t)N_NODES * 64 * 4;
  uint16_t* mbuf   = (uint16_t*)w;  w += (size_t)N_NODES * 192 * 2;
  uint8_t* slot1   = (uint8_t*)w;   w += (size_t)N_NODES * 64;   // fp8 h-shadow 1 / Pb
  uint8_t* slot2   = (uint8_t*)w;   w += (size_t)N_NODES * 64;   // fp8 h-shadow 2 / Qb
  uint8_t* hf8_1   = slot1;
  uint8_t* hf8_2   = slot2;
  uint8_t* Pb      = slot1;                      // hf8_1 dead after first k_agg
  uint8_t* Qb      = slot2;                      // hf8_2 dead after second k_agg
  uint32_t* pairbuf = (uint32_t*)h1;             // 12.81 MB, aliases h1+h2 head
  int* excl        = (int*)mbuf;                 // dead until first k_agg
  int* bsum        = (int*)mbuf + N_NODES;

  hipMemsetAsync(bcur, 0, (size_t)NB * 4, stream);

  k_prep   <<<NWG_PREP, 256, 0, stream>>>(ei, ea, bcur, pairbuf);
  k_count  <<<NB, 256, 0, stream>>>(pairbuf, bcur, cnt3);
  k_scanA  <<<NBLK_N, 256, 0, stream>>>(cnt3, excl, bsum);
  k_scanB  <<<1, 256, 0, stream>>>(bsum);
  k_scanC  <<<NBLK_N, 256, 0, stream>>>(cnt3, excl, bsum, meta, x, x4);
  k_scat2  <<<NB, 256, 0, stream>>>(pairbuf, bcur, meta, csr);

  k_layer0 <<<N_NODES / 4, 256, 0, stream>>>(x4, w0, root0, b0, meta, csr, h1, hf8_1);

  k_agg    <<<N_NODES / 4, 256, 0, stream>>>(hf8_1, meta, csr, mbuf);
  k_gemm   <<<(N_NODES + 31) / 32, 256, 0, stream>>>(h1, mbuf, w1, root1, b1, h2, hf8_2);

  k_agg    <<<N_NODES / 4, 256, 0, stream>>>(hf8_2, meta, csr, mbuf);
  k_gemm   <<<(N_NODES + 31) / 32, 256, 0, stream>>>(h2, mbuf, w2, root2, b2, h1, (uint8_t*)nullptr);

  k_pq2    <<<(N_NODES + 31) / 32, 256, 0, stream>>>(h1, dw1, db1, Pb, Qb);
  k_dec    <<<N_EDGES / 256, 256, 0, stream>>>(ei, ea, Pb, Qb, dw1, dw2, db2, dw3, db3, out);
}

// Round 17
// 308.225 us; speedup vs baseline: 1.0190x; 1.0190x over previous
//
#include <hip/hip_runtime.h>
#include <stdint.h>

#define N_NODES 50000
#define N_EDGES 1600000
#define NBLK_N 196        // ceil(50000/256)
#define NB 391            // buckets of 128 dst nodes
#define BPAD 8192         // padded bucket capacity
#define CHUNK 4096        // edges per prep workgroup
#define NWG_PREP 391      // ceil(1.6M/4096)

typedef float fvec2 __attribute__((ext_vector_type(2)));

__device__ inline float bf2f(uint16_t u) {
  union { uint32_t i; float f; } c; c.i = (uint32_t)u << 16; return c.f;
}
__device__ inline uint16_t f2bf(float f) {
  union { uint32_t i; float f; } c; c.f = f;
  uint32_t b = c.i;
  b += 0x7FFFu + ((b >> 16) & 1u);   // round to nearest even
  return (uint16_t)(b >> 16);
}

// hardware OCP e4m3fn helpers (gfx950 fp8-conversion-insts)
__device__ inline uint32_t pk4_fp8(float a, float b, float c, float d) {
  a = fminf(fmaxf(a, -440.0f), 440.0f);
  b = fminf(fmaxf(b, -440.0f), 440.0f);
  c = fminf(fmaxf(c, -440.0f), 440.0f);
  d = fminf(fmaxf(d, -440.0f), 440.0f);
  int pk = __builtin_amdgcn_cvt_pk_fp8_f32(a, b, 0, false);
  pk = __builtin_amdgcn_cvt_pk_fp8_f32(c, d, pk, true);
  return (uint32_t)pk;
}

// ---------------------------------------------------------------------------
// Prep + pass-1 binning (no global cnt3 atomics)
// ---------------------------------------------------------------------------
__global__ __launch_bounds__(256) void k_prep(const int* __restrict__ ei,
                                              const float* __restrict__ ea,
                                              int* __restrict__ bcur,
                                              uint32_t* __restrict__ pairbuf) {
  __shared__ int hist[NB];
  __shared__ int hbase[NB];
  int t = threadIdx.x;
  int base = blockIdx.x * CHUNK;
  for (int i = t; i < NB; i += 256) hist[i] = 0;
  __syncthreads();

  uint32_t wreg[16];
  int breg[16];
  #pragma unroll
  for (int k = 0; k < 16; k++) {
    int e = base + t + k * 256;
    breg[k] = -1;
    if (e < N_EDGES) {
      float dist = ea[(size_t)e * 6];
      int rel = (dist > 5000.0f) + (dist > 10000.0f);
      int s = ei[e];
      int d = ei[N_EDGES + e];
      wreg[k] = (uint32_t)s | ((uint32_t)rel << 16) | ((uint32_t)(d & 127) << 24);
      breg[k] = d >> 7;
      atomicAdd(&hist[breg[k]], 1);
    }
  }
  __syncthreads();
  for (int i = t; i < NB; i += 256) {
    int h = hist[i];
    hbase[i] = h ? atomicAdd(&bcur[i], h) : 0;
    hist[i] = 0;
  }
  __syncthreads();
  #pragma unroll
  for (int k = 0; k < 16; k++) {
    int b = breg[k];
    if (b >= 0) {
      int r = atomicAdd(&hist[b], 1);
      pairbuf[(size_t)b * BPAD + hbase[b] + r] = wreg[k];
    }
  }
}

// ---------------------------------------------------------------------------
// Per-bucket (node,rel) counting -> cnt3
// ---------------------------------------------------------------------------
__global__ __launch_bounds__(256) void k_count(const uint32_t* __restrict__ pairbuf,
                                               const int* __restrict__ bcur,
                                               int* __restrict__ cnt3) {
  __shared__ int lc[384];
  int b = blockIdx.x;
  int t = threadIdx.x;
  for (int i = t; i < 384; i += 256) lc[i] = 0;
  int cnt = bcur[b];
  __syncthreads();
  const uint32_t* pb = pairbuf + (size_t)b * BPAD;
  for (int i = t; i < cnt; i += 256) {
    uint32_t w = pb[i];
    int dl  = (int)(w >> 24);
    int rel = (int)((w >> 16) & 3u);
    atomicAdd(&lc[dl * 3 + rel], 1);
  }
  __syncthreads();
  int gbase = b * 384;
  for (int j = t; j < 384; j += 256) {
    int node = (b << 7) + (j / 3);
    if (node < N_NODES) cnt3[gbase + j] = lc[j];
  }
}

// ---------------------------------------------------------------------------
// Parallel scan of node degrees
// ---------------------------------------------------------------------------
__global__ __launch_bounds__(256) void k_scanA(const int* __restrict__ cnt3,
                                               int* __restrict__ excl,
                                               int* __restrict__ bsum) {
  __shared__ int s[256];
  int t = threadIdx.x;
  int n = blockIdx.x * 256 + t;
  int deg = 0;
  if (n < N_NODES) deg = cnt3[3 * n] + cnt3[3 * n + 1] + cnt3[3 * n + 2];
  s[t] = deg;
  __syncthreads();
  for (int ofs = 1; ofs < 256; ofs <<= 1) {
    int v = (t >= ofs) ? s[t - ofs] : 0;
    __syncthreads();
    s[t] += v;
    __syncthreads();
  }
  if (n < N_NODES) excl[n] = s[t] - deg;
  if (t == 255) bsum[blockIdx.x] = s[255];
}

__global__ __launch_bounds__(256) void k_scanB(int* __restrict__ bsum) {
  __shared__ int s[256];
  int t = threadIdx.x;
  int v = (t < NBLK_N) ? bsum[t] : 0;
  s[t] = v;
  __syncthreads();
  for (int ofs = 1; ofs < 256; ofs <<= 1) {
    int u = (t >= ofs) ? s[t - ofs] : 0;
    __syncthreads();
    s[t] += u;
    __syncthreads();
  }
  if (t < NBLK_N) bsum[t] = s[t] - v;   // exclusive
}

__global__ __launch_bounds__(256) void k_scanC(const int* __restrict__ cnt3,
                                               const int* __restrict__ excl,
                                               const int* __restrict__ bsum,
                                               int4* __restrict__ meta,
                                               const float* __restrict__ x,
                                               float4* __restrict__ x4) {
  int n = blockIdx.x * 256 + threadIdx.x;
  if (n >= N_NODES) return;
  meta[n] = make_int4(bsum[blockIdx.x] + excl[n],
                      cnt3[3 * n], cnt3[3 * n + 1], cnt3[3 * n + 2]);
  x4[n] = make_float4(x[n * 3], x[n * 3 + 1], x[n * 3 + 2], 0.0f);
}

// ---------------------------------------------------------------------------
// Pass-2 scatter
// ---------------------------------------------------------------------------
__global__ __launch_bounds__(256) void k_scat2(const uint32_t* __restrict__ pairbuf,
                                               const int* __restrict__ bcur,
                                               const int4* __restrict__ meta,
                                               uint32_t* __restrict__ csr) {
  __shared__ int lcur[128];
  int b = blockIdx.x;
  int t = threadIdx.x;
  int node0 = b << 7;
  if (t < 128) {
    int n = node0 + t;
    lcur[t] = (n < N_NODES) ? meta[n].x : 0;
  }
  int cnt = bcur[b];
  __syncthreads();
  const uint32_t* pb = pairbuf + (size_t)b * BPAD;
  for (int i = t; i < cnt; i += 256) {
    uint32_t w = pb[i];
    int dl = (int)(w >> 24);
    int p = atomicAdd(&lcur[dl], 1);
    csr[p] = w & 0x00FFFFFFu;   // src | rel<<16
  }
}

// ---------------------------------------------------------------------------
// Layer 0: din=3. Wave per node; writes f32 h + fp8 shadow (64 B rows).
// ---------------------------------------------------------------------------
__global__ __launch_bounds__(256) void k_layer0(const float4* __restrict__ x4,
                                                const float* __restrict__ W0,
                                                const float* __restrict__ root0,
                                                const float* __restrict__ b0,
                                                const int4* __restrict__ meta,
                                                const uint32_t* __restrict__ csr,
                                                float* __restrict__ hout,
                                                uint8_t* __restrict__ hf8) {
  __shared__ float sW[576], sR[192], sb[64];
  int t = threadIdx.x;
  for (int i = t; i < 576; i += 256) sW[i] = W0[i];
  for (int i = t; i < 192; i += 256) sR[i] = root0[i];
  if (t < 64) sb[t] = b0[t];
  __syncthreads();
  int wid = t >> 6, lane = t & 63;
  int n = blockIdx.x * 4 + wid;
  int4 md = meta[n];
  int off = md.x, c0 = md.y, c1 = md.z, c2 = md.w;
  int cnt = c0 + c1 + c2;
  float a00 = 0, a01 = 0, a02 = 0, a10 = 0, a11 = 0, a12 = 0, a20 = 0, a21 = 0, a22 = 0;
  for (int base = 0; base < cnt; base += 64) {
    int idx = base + lane;
    float4 v = make_float4(0, 0, 0, 0);
    int r = 3;
    if (idx < cnt) {
      uint32_t u = csr[off + idx];
      r = (int)(u >> 16);
      v = x4[u & 0xFFFFu];
    }
    a00 += (r == 0) ? v.x : 0.0f; a01 += (r == 0) ? v.y : 0.0f; a02 += (r == 0) ? v.z : 0.0f;
    a10 += (r == 1) ? v.x : 0.0f; a11 += (r == 1) ? v.y : 0.0f; a12 += (r == 1) ? v.z : 0.0f;
    a20 += (r == 2) ? v.x : 0.0f; a21 += (r == 2) ? v.y : 0.0f; a22 += (r == 2) ? v.z : 0.0f;
  }
  #pragma unroll
  for (int d = 1; d < 64; d <<= 1) {
    a00 += __shfl_xor(a00, d); a01 += __shfl_xor(a01, d); a02 += __shfl_xor(a02, d);
    a10 += __shfl_xor(a10, d); a11 += __shfl_xor(a11, d); a12 += __shfl_xor(a12, d);
    a20 += __shfl_xor(a20, d); a21 += __shfl_xor(a21, d); a22 += __shfl_xor(a22, d);
  }
  float i0 = 1.0f / (float)(c0 > 1 ? c0 : 1);
  float i1 = 1.0f / (float)(c1 > 1 ? c1 : 1);
  float i2 = 1.0f / (float)(c2 > 1 ? c2 : 1);
  float4 xn = x4[n];
  float in[12];
  in[0] = xn.x; in[1] = xn.y; in[2] = xn.z;
  in[3] = a00 * i0; in[4] = a01 * i0; in[5] = a02 * i0;
  in[6] = a10 * i1; in[7] = a11 * i1; in[8] = a12 * i1;
  in[9] = a20 * i2; in[10] = a21 * i2; in[11] = a22 * i2;
  float acc = sb[lane];
  #pragma unroll
  for (int k = 0; k < 3; k++) acc = fmaf(in[k], sR[k * 64 + lane], acc);
  #pragma unroll
  for (int k = 0; k < 9; k++) acc = fmaf(in[3 + k], sW[k * 64 + lane], acc);
  float h = fmaxf(acc, 0.0f);
  hout[(size_t)n * 64 + lane] = h;
  float hc = fminf(h, 440.0f);
  int p8 = __builtin_amdgcn_cvt_pk_fp8_f32(hc, hc, 0, false);
  hf8[(size_t)n * 64 + lane] = (uint8_t)(p8 & 0xFF);
}

// ---------------------------------------------------------------------------
// Aggregation: wave per node, lane = feature, fp8 gathers; 16-deep unroll.
// ---------------------------------------------------------------------------
#define ACC(E, V) { int r_ = (int)((E) >> 16); \
  a0 += (r_ == 0) ? (V) : 0.0f; a1 += (r_ == 1) ? (V) : 0.0f; a2 += (r_ == 2) ? (V) : 0.0f; }

__global__ __launch_bounds__(256) void k_agg(const uint8_t* __restrict__ hf8,
                                             const int4* __restrict__ meta,
                                             const uint32_t* __restrict__ csr,
                                             uint16_t* __restrict__ mbuf) {
  int t = threadIdx.x, wid = t >> 6, lane = t & 63;
  int n = blockIdx.x * 4 + wid;
  int4 md = meta[n];
  int off = __builtin_amdgcn_readfirstlane(md.x);
  int c0  = __builtin_amdgcn_readfirstlane(md.y);
  int c1  = __builtin_amdgcn_readfirstlane(md.z);
  int c2  = __builtin_amdgcn_readfirstlane(md.w);
  int cnt = c0 + c1 + c2;
  const uint32_t* cp = csr + off;
  float a0 = 0, a1 = 0, a2 = 0;
  int i = 0;
  for (; i + 16 <= cnt; i += 16) {
    uint32_t ew[16];
    int bw[16];
    #pragma unroll
    for (int k = 0; k < 16; k++) ew[k] = cp[i + k];
    #pragma unroll
    for (int k = 0; k < 16; k++) bw[k] = hf8[(int)((ew[k] & 0xFFFFu) << 6) + lane];
    #pragma unroll
    for (int k = 0; k < 16; k++) {
      float v = __builtin_amdgcn_cvt_f32_fp8(bw[k], 0);
      ACC(ew[k], v)
    }
  }
  for (; i + 8 <= cnt; i += 8) {
    uint32_t ew[8];
    int bw[8];
    #pragma unroll
    for (int k = 0; k < 8; k++) ew[k] = cp[i + k];
    #pragma unroll
    for (int k = 0; k < 8; k++) bw[k] = hf8[(int)((ew[k] & 0xFFFFu) << 6) + lane];
    #pragma unroll
    for (int k = 0; k < 8; k++) {
      float v = __builtin_amdgcn_cvt_f32_fp8(bw[k], 0);
      ACC(ew[k], v)
    }
  }
  for (; i < cnt; i++) {
    uint32_t e = cp[i];
    int b = hf8[(int)((e & 0xFFFFu) << 6) + lane];
    float v = __builtin_amdgcn_cvt_f32_fp8(b, 0);
    ACC(e, v)
  }
  uint16_t* mb = mbuf + (size_t)n * 192;
  mb[lane]       = f2bf(a0 * (1.0f / (float)(c0 > 1 ? c0 : 1)));
  mb[64 + lane]  = f2bf(a1 * (1.0f / (float)(c1 > 1 ? c1 : 1)));
  mb[128 + lane] = f2bf(a2 * (1.0f / (float)(c2 > 1 ? c2 : 1)));
}

// ---------------------------------------------------------------------------
// Transform GEMM: BM=32 tile. A = [h(f32) | means(bf16)]. Epilogue f32 h
// (+ optional fp8 shadow).
// ---------------------------------------------------------------------------
__global__ __launch_bounds__(256) void k_gemm(const float* __restrict__ hin,
                                              const uint16_t* __restrict__ mbuf,
                                              const float* __restrict__ W,
                                              const float* __restrict__ root,
                                              const float* __restrict__ b,
                                              float* __restrict__ hout,
                                              uint8_t* __restrict__ hf8) {
  __shared__ float As[32 * 84];
  __shared__ float Bs[64 * 64];
  __shared__ float sb[64];
  int t = threadIdx.x;
  int bn = blockIdx.x * 32;
  if (t < 64) sb[t] = b[t];
  int tn = t & 15, to = t >> 4;
  float acc[2][4] = {};
  for (int kb = 0; kb < 4; kb++) {
    const float4* Bsrc = (const float4*)((kb == 0) ? root : (W + (size_t)(kb - 1) * 4096));
    for (int i2 = t; i2 < 1024; i2 += 256) ((float4*)Bs)[i2] = Bsrc[i2];
    int r = t >> 3;                   // 32 rows, 8 threads/row
    int node = bn + r;
    bool ok = node < N_NODES;
    if (kb == 0) {
      const float* Arow = hin + (size_t)node * 64;
      #pragma unroll
      for (int ii = 0; ii < 2; ii++) {
        int c4 = (t & 7) + 8 * ii;
        float4 v = ok ? ((const float4*)Arow)[c4] : make_float4(0, 0, 0, 0);
        *(float4*)&As[r * 84 + c4 * 4] = v;
      }
    } else {
      int c8 = t & 7;                 // 8 bf16 per thread
      const uint16_t* Mrow = mbuf + (size_t)node * 192 + (size_t)(kb - 1) * 64 + c8 * 8;
      uint4 mv = ok ? *(const uint4*)Mrow : make_uint4(0, 0, 0, 0);
      const uint32_t* mw = &mv.x;
      float f[8];
      #pragma unroll
      for (int jj = 0; jj < 4; jj++) {
        f[2 * jj]     = bf2f((uint16_t)(mw[jj] & 0xFFFFu));
        f[2 * jj + 1] = bf2f((uint16_t)(mw[jj] >> 16));
      }
      *(float4*)&As[r * 84 + c8 * 8]     = make_float4(f[0], f[1], f[2], f[3]);
      *(float4*)&As[r * 84 + c8 * 8 + 4] = make_float4(f[4], f[5], f[6], f[7]);
    }
    __syncthreads();
    #pragma unroll
    for (int k4 = 0; k4 < 16; k4++) {
      float4 a0 = *(const float4*)&As[(tn)      * 84 + k4 * 4];
      float4 a1 = *(const float4*)&As[(tn + 16) * 84 + k4 * 4];
      float4 b0 = *(const float4*)&Bs[(k4 * 4 + 0) * 64 + to * 4];
      float4 b1 = *(const float4*)&Bs[(k4 * 4 + 1) * 64 + to * 4];
      float4 b2 = *(const float4*)&Bs[(k4 * 4 + 2) * 64 + to * 4];
      float4 b3 = *(const float4*)&Bs[(k4 * 4 + 3) * 64 + to * 4];
      const float* av[2] = {&a0.x, &a1.x};
      const float* bv[4] = {&b0.x, &b1.x, &b2.x, &b3.x};
      #pragma unroll
      for (int c = 0; c < 4; c++)
        #pragma unroll
        for (int i3 = 0; i3 < 2; i3++)
          #pragma unroll
          for (int j = 0; j < 4; j++)
            acc[i3][j] = fmaf(av[i3][c], bv[c][j], acc[i3][j]);
    }
    __syncthreads();
  }
  #pragma unroll
  for (int i3 = 0; i3 < 2; i3++) {
    int node = bn + tn + 16 * i3;
    if (node < N_NODES) {
      float4 o;
      o.x = fmaxf(acc[i3][0] + sb[to * 4 + 0], 0.0f);
      o.y = fmaxf(acc[i3][1] + sb[to * 4 + 1], 0.0f);
      o.z = fmaxf(acc[i3][2] + sb[to * 4 + 2], 0.0f);
      o.w = fmaxf(acc[i3][3] + sb[to * 4 + 3], 0.0f);
      *(float4*)(hout + (size_t)node * 64 + to * 4) = o;
      if (hf8) {
        uint32_t pk = pk4_fp8(o.x, o.y, o.z, o.w);
        *(uint32_t*)(hf8 + (size_t)node * 64 + to * 4) = pk;
      }
    }
  }
}

// ---------------------------------------------------------------------------
// P/Q projection GEMM (BM=32): fp8 e4m3fn outputs, hardware encode.
// ---------------------------------------------------------------------------
__global__ __launch_bounds__(256) void k_pq2(const float* __restrict__ h,
                                             const float* __restrict__ dw1,
                                             const float* __restrict__ db1,
                                             uint8_t* __restrict__ Pb,
                                             uint8_t* __restrict__ Qb) {
  __shared__ float As[32 * 84];
  __shared__ float Bs[64 * 64];
  __shared__ float sdb1[32];
  int t = threadIdx.x;
  int bn = blockIdx.x * 32;
  if (t < 32) sdb1[t] = db1[t];
  {
    int r = t >> 3;
    int node = bn + r;
    bool ok = node < N_NODES;
    const float* Arow = h + (size_t)node * 64;
    #pragma unroll
    for (int ii = 0; ii < 2; ii++) {
      int c4 = (t & 7) + 8 * ii;
      float4 v = ok ? ((const float4*)Arow)[c4] : make_float4(0, 0, 0, 0);
      *(float4*)&As[r * 84 + c4 * 4] = v;
    }
  }
  for (int i = t; i < 4096; i += 256) {
    int k = i >> 6, j = i & 63;
    Bs[i] = (j < 32) ? dw1[k * 32 + j] : dw1[(64 + k) * 32 + (j - 32)];
  }
  __syncthreads();
  int tn = t & 15, to = t >> 4;
  float acc[2][4] = {};
  #pragma unroll
  for (int k4 = 0; k4 < 16; k4++) {
    float4 a0 = *(const float4*)&As[(tn)      * 84 + k4 * 4];
    float4 a1 = *(const float4*)&As[(tn + 16) * 84 + k4 * 4];
    float4 b0 = *(const float4*)&Bs[(k4 * 4 + 0) * 64 + to * 4];
    float4 b1 = *(const float4*)&Bs[(k4 * 4 + 1) * 64 + to * 4];
    float4 b2 = *(const float4*)&Bs[(k4 * 4 + 2) * 64 + to * 4];
    float4 b3 = *(const float4*)&Bs[(k4 * 4 + 3) * 64 + to * 4];
    const float* av[2] = {&a0.x, &a1.x};
    const float* bv[4] = {&b0.x, &b1.x, &b2.x, &b3.x};
    #pragma unroll
    for (int c = 0; c < 4; c++)
      #pragma unroll
      for (int i3 = 0; i3 < 2; i3++)
        #pragma unroll
        for (int j = 0; j < 4; j++)
          acc[i3][j] = fmaf(av[i3][c], bv[c][j], acc[i3][j]);
  }
  bool isP = (to < 8);
  float bias0 = isP ? sdb1[to * 4 + 0] : 0.0f;
  float bias1 = isP ? sdb1[to * 4 + 1] : 0.0f;
  float bias2 = isP ? sdb1[to * 4 + 2] : 0.0f;
  float bias3 = isP ? sdb1[to * 4 + 3] : 0.0f;
  #pragma unroll
  for (int i3 = 0; i3 < 2; i3++) {
    int node = bn + tn + 16 * i3;
    if (node < N_NODES) {
      uint32_t pk = pk4_fp8(acc[i3][0] + bias0, acc[i3][1] + bias1,
                            acc[i3][2] + bias2, acc[i3][3] + bias3);
      if (isP) *(uint32_t*)(Pb + (size_t)node * 32 + to * 4) = pk;
      else     *(uint32_t*)(Qb + (size_t)node * 32 + (to - 8) * 4) = pk;
    }
  }
}

// ---------------------------------------------------------------------------
// Decoder edge pass: fp8 P/Q gathers, hardware pk decode, vectorized LDS
// (round-15 single-edge version: 32 VGPR, ~69% occupancy, measured 55.7 us)
// ---------------------------------------------------------------------------
__global__ __launch_bounds__(256) void k_dec(const int* __restrict__ ei,
                                             const float* __restrict__ ea,
                                             const uint8_t* __restrict__ Pb,
                                             const uint8_t* __restrict__ Qb,
                                             const float* __restrict__ dw1,
                                             const float* __restrict__ dw2,
                                             const float* __restrict__ db2,
                                             const float* __restrict__ dw3,
                                             const float* __restrict__ db3,
                                             float* __restrict__ out) {
  __shared__ float C[6 * 32], W2T[16 * 32], sb2[16], W3[16];
  __shared__ float sb3;
  int t = threadIdx.x;
  for (int i = t; i < 192; i += 256) C[i] = dw1[128 * 32 + i];
  for (int i = t; i < 512; i += 256) {
    int r = i >> 5, c = i & 31;            // W2T[r][c] = dw2[c][r]
    W2T[i] = dw2[c * 16 + r];
  }
  if (t < 16) { sb2[t] = db2[t]; W3[t] = dw3[t]; }
  if (t == 0) sb3 = db3[0];
  __syncthreads();
  int e = blockIdx.x * 256 + t;
  int s = ei[e];
  int d = ei[N_EDGES + e];
  float ea6[6];
  #pragma unroll
  for (int i = 0; i < 6; i++) ea6[i] = ea[(size_t)e * 6 + i];
  uint4 pv0 = *(const uint4*)(Pb + (size_t)s * 32);
  uint4 pv1 = *(const uint4*)(Pb + (size_t)s * 32 + 16);
  uint4 qv0 = *(const uint4*)(Qb + (size_t)d * 32);
  uint4 qv1 = *(const uint4*)(Qb + (size_t)d * 32 + 16);
  uint32_t pw[8] = {pv0.x, pv0.y, pv0.z, pv0.w, pv1.x, pv1.y, pv1.z, pv1.w};
  uint32_t qw[8] = {qv0.x, qv0.y, qv0.z, qv0.w, qv1.x, qv1.y, qv1.z, qv1.w};
  float z1[32];
  #pragma unroll
  for (int w = 0; w < 8; w++) {
    fvec2 pl = __builtin_amdgcn_cvt_pk_f32_fp8((int)pw[w], false);
    fvec2 ph = __builtin_amdgcn_cvt_pk_f32_fp8((int)pw[w], true);
    fvec2 ql = __builtin_amdgcn_cvt_pk_f32_fp8((int)qw[w], false);
    fvec2 qh = __builtin_amdgcn_cvt_pk_f32_fp8((int)qw[w], true);
    float v0 = pl.x + ql.x;
    float v1 = pl.y + ql.y;
    float v2 = ph.x + qh.x;
    float v3 = ph.y + qh.y;
    #pragma unroll
    for (int k = 0; k < 6; k++) {
      float4 cv = *(const float4*)&C[k * 32 + w * 4];
      v0 = fmaf(ea6[k], cv.x, v0);
      v1 = fmaf(ea6[k], cv.y, v1);
      v2 = fmaf(ea6[k], cv.z, v2);
      v3 = fmaf(ea6[k], cv.w, v3);
    }
    z1[w * 4 + 0] = fmaxf(v0, 0.0f);
    z1[w * 4 + 1] = fmaxf(v1, 0.0f);
    z1[w * 4 + 2] = fmaxf(v2, 0.0f);
    z1[w * 4 + 3] = fmaxf(v3, 0.0f);
  }
  float o = sb3;
  #pragma unroll
  for (int i = 0; i < 16; i++) {
    float z = sb2[i];
    #pragma unroll
    for (int j4 = 0; j4 < 8; j4++) {
      float4 wv = *(const float4*)&W2T[i * 32 + j4 * 4];
      z = fmaf(z1[j4 * 4 + 0], wv.x, z);
      z = fmaf(z1[j4 * 4 + 1], wv.y, z);
      z = fmaf(z1[j4 * 4 + 2], wv.z, z);
      z = fmaf(z1[j4 * 4 + 3], wv.w, z);
    }
    o = fmaf(fmaxf(z, 0.0f), W3[i], o);
  }
  out[e] = o;
}

// ---------------------------------------------------------------------------
extern "C" void kernel_launch(void* const* d_in, const int* in_sizes, int n_in,
                              void* d_out, int out_size, void* d_ws, size_t ws_size,
                              hipStream_t stream) {
  const float* x      = (const float*)d_in[0];
  const int*   ei     = (const int*)d_in[1];
  const float* ea     = (const float*)d_in[2];
  const float* w0     = (const float*)d_in[3];
  const float* root0  = (const float*)d_in[4];
  const float* b0     = (const float*)d_in[5];
  const float* w1     = (const float*)d_in[6];
  const float* root1  = (const float*)d_in[7];
  const float* b1     = (const float*)d_in[8];
  const float* w2     = (const float*)d_in[9];
  const float* root2  = (const float*)d_in[10];
  const float* b2     = (const float*)d_in[11];
  const float* dw1    = (const float*)d_in[12];
  const float* db1    = (const float*)d_in[13];
  const float* dw2    = (const float*)d_in[14];
  const float* db2    = (const float*)d_in[15];
  const float* dw3    = (const float*)d_in[16];
  const float* db3    = (const float*)d_in[17];
  float* out = (float*)d_out;

  char* w = (char*)d_ws;
  int* cnt3        = (int*)w;       w += (size_t)N_NODES * 3 * 4;
  int* bcur        = (int*)w;       w += (size_t)NB * 4;
  int4* meta       = (int4*)w;      w += (size_t)N_NODES * 16;
  uint32_t* csr    = (uint32_t*)w;  w += (size_t)N_EDGES * 4;
  float4* x4       = (float4*)w;    w += (size_t)N_NODES * 16;
  float* h1        = (float*)w;     w += (size_t)N_NODES * 64 * 4;
  float* h2        = (float*)w;     w += (size_t)N_NODES * 64 * 4;
  uint16_t* mbuf   = (uint16_t*)w;  w += (size_t)N_NODES * 192 * 2;
  uint8_t* slot1   = (uint8_t*)w;   w += (size_t)N_NODES * 64;   // fp8 h-shadow 1 / Pb
  uint8_t* slot2   = (uint8_t*)w;   w += (size_t)N_NODES * 64;   // fp8 h-shadow 2 / Qb
  uint8_t* hf8_1   = slot1;
  uint8_t* hf8_2   = slot2;
  uint8_t* Pb      = slot1;                      // hf8_1 dead after first k_agg
  uint8_t* Qb      = slot2;                      // hf8_2 dead after second k_agg
  uint32_t* pairbuf = (uint32_t*)h1;             // 12.81 MB, aliases h1+h2 head
  int* excl        = (int*)mbuf;                 // dead until first k_agg
  int* bsum        = (int*)mbuf + N_NODES;

  hipMemsetAsync(bcur, 0, (size_t)NB * 4, stream);

  k_prep   <<<NWG_PREP, 256, 0, stream>>>(ei, ea, bcur, pairbuf);
  k_count  <<<NB, 256, 0, stream>>>(pairbuf, bcur, cnt3);
  k_scanA  <<<NBLK_N, 256, 0, stream>>>(cnt3, excl, bsum);
  k_scanB  <<<1, 256, 0, stream>>>(bsum);
  k_scanC  <<<NBLK_N, 256, 0, stream>>>(cnt3, excl, bsum, meta, x, x4);
  k_scat2  <<<NB, 256, 0, stream>>>(pairbuf, bcur, meta, csr);

  k_layer0 <<<N_NODES / 4, 256, 0, stream>>>(x4, w0, root0, b0, meta, csr, h1, hf8_1);

  k_agg    <<<N_NODES / 4, 256, 0, stream>>>(hf8_1, meta, csr, mbuf);
  k_gemm   <<<(N_NODES + 31) / 32, 256, 0, stream>>>(h1, mbuf, w1, root1, b1, h2, hf8_2);

  k_agg    <<<N_NODES / 4, 256, 0, stream>>>(hf8_2, meta, csr, mbuf);
  k_gemm   <<<(N_NODES + 31) / 32, 256, 0, stream>>>(h2, mbuf, w2, root2, b2, h1, (uint8_t*)nullptr);

  k_pq2    <<<(N_NODES + 31) / 32, 256, 0, stream>>>(h1, dw1, db1, Pb, Qb);
  k_dec    <<<N_EDGES / 256, 256, 0, stream>>>(ei, ea, Pb, Qb, dw1, dw2, db2, dw3, db3, out);
}